// Round 9
// baseline (198.319 us; speedup 1.0000x reference)
//
#include <hip/hip_runtime.h>

// CTC forward loss. T=1024, B=128, C=256, S=64, L=129.
// 3 waves per block (one block per batch element):
//   waves 1-2 (producers): per chunk, issue ALL 64 global loads first
//     (4 named 8-row register sets: gather lp[t][b][tgt_lane] + lp[t][b][0]),
//     ONE latency wait, then exp() + ds_write 32 rows of {eml,ebl} float2
//     into a 2-chunk LDS ring. R8's load/store interleave still serialized
//     (~9.6k cyc/chunk, gain ~0); loads-first guarantees one wait per chunk.
//   wave 0 (consumer): alpha recurrence in SCALED LINEAR FP64:
//     p_s = exp(alpha_s)*2^es (es = wave-uniform int exponent).
//     lane i holds p[2i] ("pa"), p[2i+1] ("pb"); lane 63 also p[128] ("pc").
//     Each 32-step half-chunk is preloaded into 32 NAMED float2 registers
//     (back-to-back ds_read_b64, in-order return -> one ~120cyc wait per 32
//     steps), then 32 pure-VALU steps. No per-step LDS access at all.
//   Rescale after every 32-step block, unconditional (power-of-2, value-
//   preserving => harmless on masked blocks): int-max DPP over f64 hi-words
//   (positive doubles order as ints), readlane, exact ldexp.

#define NEGV (-1e30f)
#define NEGH (-5e29f)

constexpr int T_  = 1024;
constexpr int C_  = 256;
constexpr int CH  = 64;        // rows per chunk
constexpr int NCH = T_ / CH;   // 16 chunks covering t = 1 .. 1024

__device__ __forceinline__ float lse2f(float x, float y) {
    float m = fmaxf(x, y);
    float s = __expf(x - m) + __expf(y - m);
    float r = m + __logf(s);
    return (m > NEGH) ? r : NEGV;
}

// double from lane i-1; lane 0 gets 0.0. Two b32 DPP wave_shr:1 (pure VALU).
__device__ __forceinline__ double dshr1(double x) {
    int lo = __double2loint(x), hi = __double2hiint(x);
    int plo = __builtin_amdgcn_update_dpp(0, lo, 0x138, 0xf, 0xf, false);
    int phi = __builtin_amdgcn_update_dpp(0, hi, 0x138, 0xf, 0xf, false);
    return __hiloint2double(phi, plo);
}

// one step of a DPP int-max reduction; old = x is identity under max
template <int CTRL>
__device__ __forceinline__ int dpp_imaxstep(int x) {
    int r = __builtin_amdgcn_update_dpp(x, x, CTRL, 0xf, 0xf, false);
    return max(x, r);
}

// ---------------- producer macros (named regs only; arrays are not promoted)
#define PD8(S) float S##0,S##1,S##2,S##3,S##4,S##5,S##6,S##7
#define PL1(G,L,J,TB) { int t_=(TB)+(J); t_ = t_>1023?1023:t_;               \
    const float* rp_ = rowb + (size_t)t_*BC; G##J = rp_[my_tgt]; L##J = rp_[0]; }
#define PL8(G,L,TB) PL1(G,L,0,TB) PL1(G,L,1,TB) PL1(G,L,2,TB) PL1(G,L,3,TB)  \
                    PL1(G,L,4,TB) PL1(G,L,5,TB) PL1(G,L,6,TB) PL1(G,L,7,TB)
#define PS1(G,L,J,RB) bp[((RB)+(J))*64 + lane] =                             \
    make_float2(__expf(G##J), __expf(L##J));
#define PS8(G,L,RB) PS1(G,L,0,RB) PS1(G,L,1,RB) PS1(G,L,2,RB) PS1(G,L,3,RB)  \
                    PS1(G,L,4,RB) PS1(G,L,5,RB) PS1(G,L,6,RB) PS1(G,L,7,RB)
// 32 rows: ALL 64 loads issued before any exp/store -> one latency wait.
#define PRODUCE32(TS,RB) {                                                   \
    PD8(Ag); PD8(Al); PD8(Bg); PD8(Bl); PD8(Cg); PD8(Cl); PD8(Dg); PD8(Dl);  \
    PL8(Ag,Al,(TS))    PL8(Bg,Bl,(TS)+8)                                     \
    PL8(Cg,Cl,(TS)+16) PL8(Dg,Dl,(TS)+24)                                    \
    PS8(Ag,Al,(RB))    PS8(Bg,Bl,(RB)+8)                                     \
    PS8(Cg,Cl,(RB)+16) PS8(Dg,Dl,(RB)+24) }

// ---------------- consumer macros
#define CL1(J) float2 e##J = sb[((ro)+(J))*64];
#define CL32 CL1(0) CL1(1) CL1(2) CL1(3) CL1(4) CL1(5) CL1(6) CL1(7)         \
             CL1(8) CL1(9) CL1(10) CL1(11) CL1(12) CL1(13) CL1(14) CL1(15)   \
             CL1(16) CL1(17) CL1(18) CL1(19) CL1(20) CL1(21) CL1(22) CL1(23) \
             CL1(24) CL1(25) CL1(26) CL1(27) CL1(28) CL1(29) CL1(30) CL1(31)

#define STEP(cur) {                                                          \
        double eml = (double)(cur).x;                                        \
        double ebl = (double)(cur).y;                                        \
        double pprev = dshr1(pb);            /* p[2i-1] */                   \
        double u  = fma(skipd, pprev, pa);   /* pa + skip*pprev */           \
        double nb = (pb + u) * eml;          /* state 2i+1 */                \
        double na = (pa + pprev) * ebl;      /* state 2i   */                \
        double nc = (pc + pb) * ebl;         /* state 128  */                \
        pa = na; pb = nb; pc = nc; }

#define FST1(J) STEP(e##J)
#define FST32 FST1(0) FST1(1) FST1(2) FST1(3) FST1(4) FST1(5) FST1(6)        \
              FST1(7) FST1(8) FST1(9) FST1(10) FST1(11) FST1(12) FST1(13)   \
              FST1(14) FST1(15) FST1(16) FST1(17) FST1(18) FST1(19)         \
              FST1(20) FST1(21) FST1(22) FST1(23) FST1(24) FST1(25)         \
              FST1(26) FST1(27) FST1(28) FST1(29) FST1(30) FST1(31)

#define MST1(J) if ((t0h + (J)) < ilen) { STEP(e##J) }
#define MST32 MST1(0) MST1(1) MST1(2) MST1(3) MST1(4) MST1(5) MST1(6)        \
              MST1(7) MST1(8) MST1(9) MST1(10) MST1(11) MST1(12) MST1(13)   \
              MST1(14) MST1(15) MST1(16) MST1(17) MST1(18) MST1(19)         \
              MST1(20) MST1(21) MST1(22) MST1(23) MST1(24) MST1(25)         \
              MST1(26) MST1(27) MST1(28) MST1(29) MST1(30) MST1(31)

#define RESCALE() {                                                          \
        int h = max(max(__double2hiint(pa), __double2hiint(pb)),             \
                    __double2hiint(pc));                                     \
        h = dpp_imaxstep<0x111>(h);   /* row_shr:1   */                      \
        h = dpp_imaxstep<0x112>(h);   /* row_shr:2   */                      \
        h = dpp_imaxstep<0x114>(h);   /* row_shr:4   */                      \
        h = dpp_imaxstep<0x118>(h);   /* row_shr:8   */                      \
        h = dpp_imaxstep<0x142>(h);   /* row_bcast:15*/                      \
        h = dpp_imaxstep<0x143>(h);   /* row_bcast:31*/                      \
        int hm = __builtin_amdgcn_readlane(h, 63);                           \
        int e = ((hm >> 20) & 0x7ff) - 1023;                                 \
        pa = ldexp(pa, -e); pb = ldexp(pb, -e); pc = ldexp(pc, -e);          \
        es += e; }

__global__ __launch_bounds__(192) void ctc_alpha_kernel(
    const float* __restrict__ lp,      // (T, B, C) log-probs
    const int* __restrict__ targets,   // (B*S,)
    const int* __restrict__ in_len,    // (B,)
    const int* __restrict__ tgt_len,   // (B,)
    float* __restrict__ partial,       // (B,) per-batch loss/tl
    int B, int S)
{
    __shared__ float2 stage[2][CH * 64];   // 64 KiB emit-pair ring
    __shared__ float sh[132];

    const int b    = blockIdx.x;
    const int tid  = threadIdx.x;
    const int wave = tid >> 6;
    const int lane = tid & 63;
    const int BC   = B * C_;
    const float* rowb = lp + (size_t)b * C_;   // row at time t: rowb + t*BC

    int my_tgt = (lane < S) ? targets[b * S + lane] : 0;
    int prev_tgt = __shfl_up(my_tgt, 1);
    const bool skip = (lane > 0) && (my_tgt != prev_tgt) && (my_tgt != 0);
    const double skipd = skip ? 1.0 : 0.0;
    const int ilen = in_len[b];

    // f64 linear-domain state: p = exp(alpha) * 2^es
    double pa = 0.0, pb = 0.0, pc = 0.0;
    int es = 0;
    if (wave == 0 && lane == 0) {
        pa = (double)__expf(rowb[0]);        // alpha0[0]
        pb = (double)__expf(rowb[my_tgt]);   // alpha0[1]
    }

    // producers prefill chunk 0 (rows t = 1 .. CH), 32 rows per wave
    if (wave >= 1) {
        const int r0 = (wave - 1) * 32;
        float2* bp = &stage[0][0];
        PRODUCE32(1 + r0, r0);
    }
    __syncthreads();   // chunk 0 staged

    for (int kc = 0; kc < NCH; ++kc) {
        if (wave >= 1) {
            if (kc + 1 < NCH) {
                const int r0 = (wave - 1) * 32;
                float2* bp = &stage[(kc + 1) & 1][0];
                PRODUCE32(1 + (kc + 1) * CH + r0, r0);
            }
        } else {
            const int t0 = 1 + kc * CH;
            const float2* sb = &stage[kc & 1][lane];   // row stride 64
            if (t0 + CH <= ilen) {
                // fast path: every step active
#pragma unroll
                for (int half = 0; half < 2; ++half) {
                    const int ro = half * 32;
                    CL32            // 32 ds_read_b64 back-to-back
                    FST32           // 32 pure-VALU steps
                    RESCALE();
                }
            } else if (t0 < ilen) {
                // boundary chunk: wave-uniform per-step mask
#pragma unroll
                for (int half = 0; half < 2; ++half) {
                    const int ro = half * 32;
                    const int t0h = t0 + ro;
                    CL32
                    MST32
                    RESCALE();      // value-preserving: safe when masked
                }
            }
        }
        __syncthreads();   // chunk boundary: stage drained, buffers swap
    }

    // Epilogue: p (f64) + es -> log-domain float, lane 0 computes the loss
    if (wave == 0) {
        const double lses = (double)es * 0.6931471805599453;
        auto logp = [&](double p) -> float {
            if (p == 0.0) return NEGV;
            int hi = __double2hiint(p), lo = __double2loint(p);
            int E = ((hi >> 20) & 0x7ff) - 1023;
            int hin = (hi & (int)0x800FFFFF) | (1023 << 20);  // mantissa in [1,2)
            double m = __hiloint2double(hin, lo);
            return (float)(__logf((float)m) + ((double)E * 0.6931471805599453 + lses));
        };
        sh[2 * lane]     = logp(pa);
        sh[2 * lane + 1] = logp(pb);
        if (lane == 63) sh[128] = logp(pc);
    }
    __syncthreads();
    if (tid == 0) {
        int tl = tgt_len[b];
        int hi2 = 2 * tl;
        float ll = lse2f(sh[hi2], sh[hi2 - 1]);
        float loss = (ll > NEGH) ? -ll : 0.f;
        partial[b] = loss / (float)tl;
    }
}

__global__ __launch_bounds__(128) void ctc_reduce_kernel(
    const float* __restrict__ partial, float* __restrict__ out, int B)
{
    float v = 0.f;
    for (int j = threadIdx.x; j < B; j += 128) v += partial[j];
#pragma unroll
    for (int off = 32; off > 0; off >>= 1)
        v += __shfl_down(v, off);       // 64-lane wave reduce
    __shared__ float ws[2];
    if ((threadIdx.x & 63) == 0) ws[threadIdx.x >> 6] = v;
    __syncthreads();
    if (threadIdx.x == 0) out[0] = (ws[0] + ws[1]) / (float)B;
}

extern "C" void kernel_launch(void* const* d_in, const int* in_sizes, int n_in,
                              void* d_out, int out_size, void* d_ws, size_t ws_size,
                              hipStream_t stream)
{
    const float* lp      = (const float*)d_in[0];  // (T,B,C) float32
    const int*   targets = (const int*)d_in[1];    // (B*S,)  int32
    const int*   il      = (const int*)d_in[2];    // (B,)
    const int*   tl      = (const int*)d_in[3];    // (B,)
    const int B = in_sizes[2];
    const int S = in_sizes[1] / B;

    float* partial = (float*)d_ws;     // B floats of scratch

    ctc_alpha_kernel<<<B, 192, 0, stream>>>(lp, targets, il, tl, partial, B, S);
    ctc_reduce_kernel<<<1, 128, 0, stream>>>(partial, (float*)d_out, B);
}